// Round 4
// baseline (178.081 us; speedup 1.0000x reference)
//
#include <hip/hip_runtime.h>
#include <cstdint>

typedef unsigned long long ull;

#define N_BOX 8192
#define CH 512        // chunk size
#define WPC 8         // words per chunk
#define NCH 16        // chunks

// ---------------- workspace layout ----------------
// TB (distance>=2 transposed col-blocks): 53760 rows * 64 B = 3,440,640 @ 0
// TC (superdiagonal transposed blocks):   15 * 32 KB        =   491,520 @ 3,440,640
// TD (per-chunk diagonal tables):         16 * 32 KB        =   524,288 @ 3,932,160
// boxesu : 8192 rows * 16 B (2 ull/row) @ 4,456,448
// scores : 32768 @ 4,587,520
// ctrl   : 68 KB @ 4,620,288
//   chunk flags: int c*32 (c<16); vb: int 512; P1 flags: int 1024+b*32;
//   P2 flags: int 9216+b*32
// keptg  : 16 chunks * 16 ull (128 B stride) @ 4,689,920
#define OFF_TB     0
#define OFF_TC     3440640
#define OFF_TD     3932160
#define OFF_BOXES  4456448
#define OFF_SCORES 4587520
#define OFF_CTRL   4620288
#define OFF_KEPT   4689920

#define CTRL_VB    512
#define P1BASE     1024
#define P2BASE     9216
#define KSTRIDE    16

// Agent(device)-scope accessors: within ONE kernel, cross-block traffic must
// bypass the per-XCD incoherent caches (no kernel-boundary flush anymore).
// Same primitives the rounds-2/3 chunk chain proved cross-XCD on this chip.
#define A_LD(p)    __hip_atomic_load((p), __ATOMIC_RELAXED, __HIP_MEMORY_SCOPE_AGENT)
#define A_LDA(p)   __hip_atomic_load((p), __ATOMIC_ACQUIRE, __HIP_MEMORY_SCOPE_AGENT)
#define A_ST(p,v)  __hip_atomic_store((p), (v), __ATOMIC_RELAXED, __HIP_MEMORY_SCOPE_AGENT)
#define A_STR(p,v) __hip_atomic_store((p), (v), __ATOMIC_RELEASE, __HIP_MEMORY_SCOPE_AGENT)

// TB rows for source chunk c' cover j >= CH*(c'+2): 7168-512c' rows (c'=0..13)
__device__ __forceinline__ int rows_before2(int c) {
    return 7424 * c - 256 * c * c;   // sum_{c'<c} (7168 - 512c')
}

__device__ __forceinline__ ull make_key(float s, int idx) {
    // positive floats: bit pattern is order-preserving. Reversed index in the
    // low 13 bits reproduces stable argsort(-conf): equal conf -> lower index first.
    return (((ull)__float_as_uint(s)) << 13) | (ull)(8191 - idx);
}

__device__ __forceinline__ float box_area(float4 b) {
    return __fmul_rn(__fsub_rn(b.z, b.x), __fsub_rn(b.w, b.y));
}

// exact replica of reference IoU rounding (_rn ops block FMA contraction); symmetric.
__device__ __forceinline__ bool iou_gt_half(float4 a, float aarea, float4 b, float barea) {
    float ix1 = fmaxf(a.x, b.x);
    float iy1 = fmaxf(a.y, b.y);
    float ix2 = fminf(a.z, b.z);
    float iy2 = fminf(a.w, b.w);
    float iw = fmaxf(__fsub_rn(ix2, ix1), 0.0f);
    float ih = fmaxf(__fsub_rn(iy2, iy1), 0.0f);
    float inter = __fmul_rn(iw, ih);
    float uni = __fsub_rn(__fadd_rn(aarea, barea), inter);
    float iou = __fdiv_rn(inter, fmaxf(uni, 1e-9f));
    return iou > 0.5f;
}

__device__ __forceinline__ float4 load_box(const ull* bu, int j) {
    ull lo = A_LD(&bu[2 * j]);
    ull hi = A_LD(&bu[2 * j + 1]);
    float4 b;
    b.x = __uint_as_float((unsigned)lo);
    b.y = __uint_as_float((unsigned)(lo >> 32));
    b.z = __uint_as_float((unsigned)hi);
    b.w = __uint_as_float((unsigned)(hi >> 32));
    return b;
}

// ONE kernel, 256 blocks x 256 threads (1 block/CU: co-residency structural).
// P1 rank+scatter -> flag barrier -> P2 table build -> flag barrier (owners)
// -> P3 chunk-chain NMS + epilogue. Owner of chunk c = block 16c (all owners
// on one XCD under round-robin dispatch -> L2-local chain hops; correctness
// does not depend on the mapping).
__global__ __launch_bounds__(256, 1) void mega(const float* __restrict__ in,
                                               ull* __restrict__ TBg,
                                               ull* __restrict__ TCg,
                                               ull* __restrict__ TDg,
                                               ull* __restrict__ boxesu,
                                               float* __restrict__ scores,
                                               int* __restrict__ ctrl,
                                               ull* __restrict__ keptg,
                                               float* __restrict__ out) {
    __shared__ ull smem[8192];        // 64 KB union: P1 keys | P2 sb+sa | P3 TDs+TCs
    __shared__ unsigned amask[16];
    __shared__ ull kwsh[WPC];
    __shared__ float wm[4];
    __shared__ int wv[4];
    const int t = threadIdx.x;
    const int bx = blockIdx.x;
    const int lane = t & 63;
    const int wave = t >> 6;

    // ================= P1: max + rank + scatter (round-3 proven shape) =====
    {
        ull* keys = smem;
        float cf[32];
        float m = 0.0f;                    // conf >= 0 so 0-seed is safe
        #pragma unroll
        for (int r = 0; r < 32; ++r) {
            cf[r] = in[(r * 256 + t) * 5 + 4];
            m = fmaxf(m, cf[r]);
        }
        for (int off = 32; off; off >>= 1) m = fmaxf(m, __shfl_down(m, off));
        if ((t & 63) == 0) wm[t >> 6] = m;
        __syncthreads();
        float maxc = fmaxf(fmaxf(wm[0], wm[1]), fmaxf(wm[2], wm[3]));

        #pragma unroll
        for (int r = 0; r < 32; ++r) {
            int k = r * 256 + t;
            keys[k] = make_key(__fdiv_rn(cf[r], maxc), k);
        }
        __syncthreads();

        // rank: 8 threads per i; seg scans {8*cc+seg}; LDS addr = base +
        // compile-time immediate (the PROVEN pipelining shape; dynamic
        // per-lane addressing was the round-2 87us disaster).
        int il = t >> 3, seg = t & 7;
        int i = bx * 32 + il;
        ull ki = keys[i];
        const ull* kb = keys + seg;
        int cnt = 0;
        #pragma unroll 8
        for (int cc = 0; cc < 1024; ++cc)
            cnt += (kb[cc * 8] > ki) ? 1 : 0;
        cnt += __shfl_down(cnt, 4, 8);
        cnt += __shfl_down(cnt, 2, 8);
        cnt += __shfl_down(cnt, 1, 8);

        if (seg == 0) {
            int r = cnt;                               // descending-sort position
            float cx = in[i * 5 + 0];
            float cy = in[i * 5 + 1];
            float w  = in[i * 5 + 2];
            float h  = in[i * 5 + 3];
            float s  = __fdiv_rn(in[i * 5 + 4], maxc);
            float bxl = __fsub_rn(cx, __fmul_rn(w, 0.5f));
            float byl = __fsub_rn(cy, __fmul_rn(h, 0.5f));
            float bxh = __fadd_rn(cx, __fmul_rn(w, 0.5f));
            float byh = __fadd_rn(cy, __fmul_rn(h, 0.5f));
            ull lo = (ull)__float_as_uint(bxl) | ((ull)__float_as_uint(byl) << 32);
            ull hi = (ull)__float_as_uint(bxh) | ((ull)__float_as_uint(byh) << 32);
            A_ST(&boxesu[2 * r], lo);
            A_ST(&boxesu[2 * r + 1], hi);
            A_ST(&scores[r], s);
        }

        // block 0: vb + zero chunk-chain flags (poisoned ws) + publish vb
        if (bx == 0) {
            const ull kthr = ((ull)0x3F000000u) << 13;   // s >= 0.5 boundary
            int cv = 0;
            for (int k = t; k < N_BOX; k += 256) cv += (keys[k] >= kthr) ? 1 : 0;
            for (int off = 32; off; off >>= 1) cv += __shfl_down(cv, off);
            if ((t & 63) == 0) wv[t >> 6] = cv;
            if (t < NCH) A_ST(&ctrl[t * 32], 0);
            __syncthreads();
            if (t == 0) A_ST(&ctrl[CTRL_VB], wv[0] + wv[1] + wv[2] + wv[3]);
        }
    }
    __syncthreads();
    if (t == 0) { __threadfence(); A_STR(&ctrl[P1BASE + bx * 32], 1); }
    // P1 barrier: thread t polls block t's flag (poison 0xAA.. != 1, fresh 0 != 1)
    while (A_LDA(&ctrl[P1BASE + t * 32]) != 1) {}
    __syncthreads();

    // ================= P2: suppression tables (k4 verbatim, grid-strided) ==
    {
        float4* sb = (float4*)smem;
        float*  sa = (float*)(smem + 1024);
        for (int tile = bx; tile < 2176; tile += 256) {
            int c, mode, j0;
            if (tile >= 1920) {
                mode = 2; int d = tile - 1920; c = d >> 4; j0 = (d & 15) * 32;
            } else if (tile >= 1680) {
                mode = 1; int d = tile - 1680; c = d >> 4; j0 = (d & 15) * 32;
            } else {
                mode = 0; c = 0; int rem = tile;
                while (rem >= 224 - 16 * c) { rem -= 224 - 16 * c; ++c; }
                j0 = CH * (c + 2) + rem * 32;
            }
            if (A_LD(&scores[c * CH]) < 0.5f) continue;          // dead source
            if (mode == 0 && A_LD(&scores[j0]) < 0.5f) continue; // dead j-tile
            __syncthreads();               // protect previous tile's sb reads
            for (int i = t; i < CH; i += 256) {
                float4 b = load_box(boxesu, c * CH + i);
                sb[i] = b;
                sa[i] = box_area(b);
            }
            __syncthreads();
            int w = t & 7;
            int r = t >> 3;
            if (mode == 2) {
                int jl = j0 + r;
                float4 me = sb[jl];
                float ma = sa[jl];
                int wj = jl >> 6;
                int lim = (w < wj) ? 64 : ((w == wj) ? (jl & 63) : 0);
                ull bits = 0;
                for (int k = 0; k < lim; ++k)
                    if (iou_gt_half(sb[w * 64 + k], sa[w * 64 + k], me, ma)) bits |= 1ull << k;
                A_ST(&TDg[c * 4096 + w * 512 + jl], bits);
            } else if (mode == 1) {
                int jl = j0 + r;
                float4 me = load_box(boxesu, CH * (c + 1) + jl);
                float ma = box_area(me);
                ull bits = 0;
                for (int k = 0; k < 64; ++k)
                    if (iou_gt_half(sb[w * 64 + k], sa[w * 64 + k], me, ma)) bits |= 1ull << k;
                A_ST(&TCg[c * 4096 + w * 512 + jl], bits);
            } else {
                int j = j0 + r;
                float4 me = load_box(boxesu, j);
                float ma = box_area(me);
                ull bits = 0;
                for (int k = 0; k < 64; ++k)
                    if (iou_gt_half(sb[w * 64 + k], sa[w * 64 + k], me, ma)) bits |= 1ull << k;
                A_ST(&TBg[(size_t)(rows_before2(c) + (j - CH * (c + 2))) * WPC + w], bits);
            }
        }
    }
    __syncthreads();
    if (t == 0) { __threadfence(); A_STR(&ctrl[P2BASE + bx * 32], 1); }

    // ================= P3: chunk-chain NMS (owners = blocks 16c) ===========
    if (bx & 15) return;                   // non-owners done (flag already set)
    int c = bx >> 4;
    while (A_LDA(&ctrl[P2BASE + t * 32]) != 1) {}   // wait ALL builds
    __syncthreads();
    int vb = A_LD(&ctrl[CTRL_VB]);
    int nchv = (vb + CH - 1) / CH;

    if (c >= nchv) {                       // dead chunk: zero its 512 rows
        #pragma unroll
        for (int rr = 0; rr < 2; ++rr) {
            int j = c * CH + rr * 256 + t;
            out[j * 5 + 0] = 0.0f; out[j * 5 + 1] = 0.0f; out[j * 5 + 2] = 0.0f;
            out[j * 5 + 3] = 0.0f; out[j * 5 + 4] = 0.0f;
        }
        return;
    }

    ull* TDs = smem;                       // 32 KB
    ull* TCs = smem + 4096;                // 32 KB
    for (int i = t; i < 4096; i += 256) TDs[i] = A_LD(&TDg[c * 4096 + i]);
    if (c > 0)
        for (int i = t; i < 4096; i += 256) TCs[i] = A_LD(&TCg[(c - 1) * 4096 + i]);
    if (t < 16) {
        int n = vb - (c * 16 + t) * 32;
        amask[t] = (n >= 32) ? 0xffffffffu : ((n <= 0) ? 0u : ((1u << n) - 1u));
    }
    __syncthreads();

    // ---- TB applies: kept[cp] -> own chunk, cp = 0..c-2 (early flags are
    // long since set; the cp=c-2 apply hides in the wait for flag[c-1]) ----
    for (int cp = 0; cp + 2 <= c; ++cp) {
        if (t == 0) {
            while (A_LDA(&ctrl[cp * 32]) != 1) {}
            #pragma unroll
            for (int w = 0; w < WPC; ++w) kwsh[w] = A_LD(&keptg[cp * KSTRIDE + w]);
        }
        __syncthreads();
        ull anyk = kwsh[0] | kwsh[1] | kwsh[2] | kwsh[3] |
                   kwsh[4] | kwsh[5] | kwsh[6] | kwsh[7];
        if (anyk) {
            #pragma unroll
            for (int rr = 0; rr < 2; ++rr) {
                int jl = rr * 256 + t;
                if ((amask[jl >> 5] >> (jl & 31)) & 1u) {
                    const ull* row = TBg +
                        (size_t)(rows_before2(cp) + (c * CH + jl - CH * (cp + 2))) * WPC;
                    ull a = 0;
                    #pragma unroll
                    for (int q = 0; q < WPC; ++q) a |= A_LD(&row[q]) & kwsh[q];
                    if (a) atomicAnd(&amask[jl >> 5], ~(1u << (jl & 31)));
                }
            }
        }
        __syncthreads();
    }

    // ---- TC apply: kept[c-1] -> own chunk (4 waves x 2 target words) ----
    if (c > 0) {
        if (t == 0) {
            while (A_LDA(&ctrl[(c - 1) * 32]) != 1) {}
            #pragma unroll
            for (int w = 0; w < WPC; ++w) kwsh[w] = A_LD(&keptg[(c - 1) * KSTRIDE + w]);
        }
        __syncthreads();
        for (int tw = wave; tw < 8; tw += 4) {
            bool dead = false;
            #pragma unroll
            for (int w = 0; w < WPC; ++w) {
                ull kw = kwsh[w];
                if (kw) dead |= (TCs[w * 512 + tw * 64 + lane] & kw) != 0ull;
            }
            ull d = __ballot(dead);
            if (lane == 0 && d) {
                amask[2 * tw]     &= ~(unsigned)d;
                amask[2 * tw + 1] &= ~(unsigned)(d >> 32);
            }
        }
        __syncthreads();
    }

    // ---- scan own chunk (wave 0): TD fixpoint, then publish ----
    if (wave == 0) {
        ull alive[WPC];
        #pragma unroll
        for (int w = 0; w < WPC; ++w)
            alive[w] = (ull)amask[2 * w] | ((ull)amask[2 * w + 1] << 32);
        const ull* T = TDs;
        #pragma unroll
        for (int w = 0; w < WPC; ++w) {
            ull word = alive[w];
            if (!word) continue;
            ull Tc[WPC];
            #pragma unroll
            for (int j = 0; j < WPC; ++j)
                if (j >= w) Tc[j] = T[w * 512 + j * 64 + lane];
            ull td = Tc[w];
            ull a2 = word, kept = 0;
            while (a2 & ~kept) {
                bool al = (a2 >> lane) & 1;
                bool kp = (kept >> lane) & 1;
                ull nk = __ballot(al && !kp && ((td & a2) == 0));
                ull nd = __ballot(al && !kp && ((td & kept) != 0));
                kept |= nk;
                a2 &= ~nd;
            }
            alive[w] = kept;
            #pragma unroll
            for (int j = 0; j < WPC; ++j) {
                if (j <= w) continue;
                if (!alive[j]) continue;
                alive[j] &= ~__ballot((Tc[j] & kept) != 0);
            }
        }
        if (lane == 0) {
            #pragma unroll
            for (int w = 0; w < WPC; ++w) {
                A_ST(&keptg[c * KSTRIDE + w], alive[w]);
                amask[2 * w]     = (unsigned)alive[w];
                amask[2 * w + 1] = (unsigned)(alive[w] >> 32);
            }
            __threadfence();
            A_STR(&ctrl[c * 32], 1);
        }
    }
    __syncthreads();

    // ---- epilogue: own 512 output rows ----
    #pragma unroll
    for (int rr = 0; rr < 2; ++rr) {
        int jl = rr * 256 + t;
        int j = c * CH + jl;
        bool kept = (amask[jl >> 5] >> (jl & 31)) & 1u;
        float4 b = load_box(boxesu, j);
        float s = A_LD(&scores[j]);
        out[j * 5 + 0] = kept ? b.x : 0.0f;
        out[j * 5 + 1] = kept ? b.y : 0.0f;
        out[j * 5 + 2] = kept ? b.z : 0.0f;
        out[j * 5 + 3] = kept ? b.w : 0.0f;
        out[j * 5 + 4] = kept ? s   : 0.0f;
    }
}

extern "C" void kernel_launch(void* const* d_in, const int* in_sizes, int n_in,
                              void* d_out, int out_size, void* d_ws, size_t ws_size,
                              hipStream_t stream) {
    const float* in = (const float*)d_in[0];
    char* ws = (char*)d_ws;
    ull* TB       = (ull*)(ws + OFF_TB);
    ull* TC       = (ull*)(ws + OFF_TC);
    ull* TD       = (ull*)(ws + OFF_TD);
    ull* boxesu   = (ull*)(ws + OFF_BOXES);
    float* scores = (float*)(ws + OFF_SCORES);
    int* ctrl     = (int*)(ws + OFF_CTRL);
    ull* keptg    = (ull*)(ws + OFF_KEPT);
    float* out    = (float*)d_out;

    mega<<<256, 256, 0, stream>>>(in, TB, TC, TD, boxesu, scores, ctrl, keptg, out);
}